// Round 4
// baseline (478.691 us; speedup 1.0000x reference)
//
#include <hip/hip_runtime.h>
#include <hip/hip_fp16.h>
#include <math.h>

#define NN 100000
#define IN_DIM 256
#define HCH 128      // HEADS*HID
#define OUT_DIM 64
#define EE 1600000
#define NEG_SLOPE 0.2f

#define NB 1024      // dst buckets per layer
#define NPB 98       // nodes per bucket (1024*98 >= 100000)
#define CAP 2048     // bucket capacity (mean 1562, std ~40 -> 12 sigma margin)

#define GEMM_BLOCKS 1563     // (NN+63)/64
#define CONV_BLOCKS 320      // (2*256*128 + 256*64)/256
#define BUCKET_PER_LAYER 512 // 512 blocks x 3125 edges
#define SORT_BLOCKS (2 * NB)

typedef _Float16 half8v __attribute__((ext_vector_type(8)));
typedef _Float16 half4v __attribute__((ext_vector_type(4)));
typedef __fp16 fp16x2 __attribute__((ext_vector_type(2)));   // clang builtin half2 type
typedef float float4v __attribute__((ext_vector_type(4)));
typedef unsigned int u32;

union H2U { u32 u; fp16x2 h; };

__device__ __forceinline__ float lrelu(float v) { return v > 0.f ? v : NEG_SLOPE * v; }

// =================== PREP: convw (blocks 0..319)  ||  bucket (1024 blocks) ==
// convw: wt[l][col][k] = W_l[k][col] fp16 ; fcw2[col][k] = fcW[k][col] (K=256)
// bucket: scatter edges into 1024 dst-region buckets, both layers.
__global__ __launch_bounds__(256, 8) void prep_kernel(
    const float* __restrict__ W0, const float* __restrict__ W1,
    const float* __restrict__ fcW,
    _Float16* __restrict__ wt, _Float16* __restrict__ fcw2,
    const int* __restrict__ ei0, const int* __restrict__ ei1,
    int* __restrict__ gcursor, int* __restrict__ bstore)
{
    __shared__ int hist[NB];
    __shared__ int base[NB];
    const int tid = threadIdx.x;

    if (blockIdx.x < CONV_BLOCKS) {
        int i = blockIdx.x * 256 + tid;
        if (i < 2 * IN_DIM * HCH) {
            int l = i >> 15, rem = i & 32767;
            int c = rem >> 8, k = rem & 255;
            const float* W = l ? W1 : W0;
            wt[i] = (_Float16)W[(size_t)k * HCH + c];
            return;
        }
        int j = i - 2 * IN_DIM * HCH;
        if (j < 256 * OUT_DIM) {
            int c = j >> 8, k = j & 255;   // fcw2[c*256 + k] = fcW[k][c]
            fcw2[j] = (_Float16)fcW[(size_t)k * OUT_DIM + c];
        }
        return;
    }

    // ---- bucket role ----
    const int bb = blockIdx.x - CONV_BLOCKS;       // 0..1023
    const int lay = bb >> 9;                       // 512 blocks per layer
    const int idx = bb & 511;
    const int* src = lay ? ei1 : ei0;
    const int* dst = src + EE;
    int* gcur = gcursor + lay * NB;
    int* bst = bstore + (size_t)lay * NB * CAP;

    const int per = (EE + BUCKET_PER_LAYER - 1) / BUCKET_PER_LAYER;  // 3125
    const int e0 = idx * per;
    const int e1 = min(EE, e0 + per);
    for (int i = tid; i < NB; i += 256) hist[i] = 0;
    __syncthreads();
    for (int i = e0 + tid; i < e1; i += 256)
        atomicAdd(&hist[dst[i] / NPB], 1);
    __syncthreads();
    for (int b = tid; b < NB; b += 256) {
        int c = hist[b];
        base[b] = c ? atomicAdd(&gcur[b], c) : 0;
        hist[b] = 0;
    }
    __syncthreads();
    for (int i = e0 + tid; i < e1; i += 256) {
        int d = dst[i];
        int s = src[i];
        int b = d / NPB;
        int pos = base[b] + atomicAdd(&hist[b], 1);
        if (pos >= 0 && pos < CAP) bst[b * CAP + pos] = (s << 7) | (d - b * NPB);
    }
}

// =================== MID: gemm (1563 blocks)  ||  sort (2048 blocks) ========
// Roles interleaved by a multiplicative split so MFMA-heavy gemm blocks and
// memory/LDS-heavy sort blocks are co-resident from the start.
__global__ __launch_bounds__(256, 3) void mid_kernel(
    const float* __restrict__ x, const _Float16* __restrict__ wt,
    const float* __restrict__ attS0, const float* __restrict__ attD0,
    const float* __restrict__ attS1, const float* __restrict__ attD1,
    _Float16* __restrict__ h16, float* __restrict__ a_s, float* __restrict__ a_d,
    const int* __restrict__ gcursor, int* __restrict__ bstore,
    int* __restrict__ gstart, int* __restrict__ gend, int n)
{
    __shared__ __align__(16) _Float16 smem[64 * 72 + 256 * 72];  // 46.1 KB
    __shared__ float attv[4][128];
    const int tid = threadIdx.x;

    const long long TS = SORT_BLOCKS;                  // 2048
    const long long TB = GEMM_BLOCKS + SORT_BLOCKS;    // 3611
    const int k = blockIdx.x;
    const int slo = (int)(((long long)k * TS) / TB);
    const int shi = (int)(((long long)(k + 1) * TS) / TB);

    if (shi > slo) {
        // ---- sort role: per-bucket LDS counting sort (in place) ----
        int* raw = (int*)smem;
        int* sorted = raw + CAP;
        int* curs = sorted + CAP;
        int* scanbuf = curs + 128;
        const int sb = slo;                  // 0..2047
        const int lay = sb >> 10;
        const int b = sb & (NB - 1);
        const int* gcur = gcursor + lay * NB;
        int* bst = bstore + (size_t)lay * NB * CAP;
        int* gs = gstart + (size_t)lay * NN;
        int* ge = gend + (size_t)lay * NN;

        const int node0 = b * NPB;
        const int nnode = min(NPB, n - node0);
        if (nnode <= 0) return;
        int cnt = gcur[b];
        cnt = cnt < 0 ? 0 : (cnt > CAP ? CAP : cnt);

        for (int i = tid; i < cnt; i += 256) raw[i] = bst[b * CAP + i];
        if (tid < 128) curs[tid] = 0;
        __syncthreads();
        for (int i = tid; i < cnt; i += 256) atomicAdd(&curs[raw[i] & 127], 1);
        __syncthreads();
        if (tid < 128) scanbuf[tid] = curs[tid];
        __syncthreads();
        for (int off = 1; off < 128; off <<= 1) {
            int v = 0;
            if (tid < 128) { v = scanbuf[tid]; if (tid >= off) v += scanbuf[tid - off]; }
            __syncthreads();
            if (tid < 128) scanbuf[tid] = v;
            __syncthreads();
        }
        if (tid < 128) {
            int ex = tid ? scanbuf[tid - 1] : 0;
            curs[tid] = ex;
            if (tid < nnode) {
                gs[node0 + tid] = b * CAP + ex;
                ge[node0 + tid] = b * CAP + scanbuf[tid];
            }
        }
        __syncthreads();
        for (int i = tid; i < cnt; i += 256) {
            int item = raw[i];
            int pos = atomicAdd(&curs[item & 127], 1);
            if (pos >= 0 && pos < CAP) sorted[pos] = item >> 7;
        }
        __syncthreads();
        for (int i = tid; i < cnt; i += 256) bst[b * CAP + i] = sorted[i];
        return;
    }

    // ---- gemm role: fused dual-layer GEMM + attention-score epilogue ----
    _Float16 (*As)[72] = (_Float16(*)[72])smem;
    _Float16 (*Bs)[72] = (_Float16(*)[72])(smem + 64 * 72);
    const int gb = k - slo;                  // 0..1562
    const int lane = tid & 63, wave = tid >> 6;
    const int wm = wave & 1, wn = wave >> 1;
    const int q = lane >> 4, r16 = lane & 15;
    const int row0 = gb * 64;

    if (tid < 128) {
        attv[0][tid] = attS0[tid]; attv[1][tid] = attD0[tid];
        attv[2][tid] = attS1[tid]; attv[3][tid] = attD1[tid];
    }

    float4v acc[2][8];
#pragma unroll
    for (int i = 0; i < 2; ++i)
#pragma unroll
        for (int j = 0; j < 8; ++j) acc[i][j] = (float4v){0.f, 0.f, 0.f, 0.f};

    const int ar = tid >> 2, aq = tid & 3;   // A: row, k-quarter (16 floats)
    const bool rok = (row0 + ar) < n;
    for (int kt = 0; kt < IN_DIM; kt += 64) {
        const float* xp = x + (size_t)(row0 + ar) * IN_DIM + kt + aq * 16;
#pragma unroll
        for (int i = 0; i < 4; ++i) {
            float4 v = rok ? *(const float4*)(xp + i * 4) : make_float4(0.f, 0.f, 0.f, 0.f);
            half4v hv = { (_Float16)v.x, (_Float16)v.y, (_Float16)v.z, (_Float16)v.w };
            *(half4v*)&As[ar][aq * 16 + i * 4] = hv;
        }
        const _Float16* wp = wt + (size_t)tid * IN_DIM + kt;
#pragma unroll
        for (int i = 0; i < 8; ++i)
            *(half8v*)&Bs[tid][i * 8] = *(const half8v*)(wp + i * 8);
        __syncthreads();
#pragma unroll
        for (int s = 0; s < 2; ++s) {
            half8v af[2], bf[8];
#pragma unroll
            for (int t = 0; t < 2; ++t)
                af[t] = *(half8v*)&As[wm * 32 + t * 16 + r16][s * 32 + q * 8];
#pragma unroll
            for (int t = 0; t < 8; ++t)
                bf[t] = *(half8v*)&Bs[wn * 128 + t * 16 + r16][s * 32 + q * 8];
#pragma unroll
            for (int mt = 0; mt < 2; ++mt)
#pragma unroll
                for (int nt = 0; nt < 8; ++nt)
                    acc[mt][nt] = __builtin_amdgcn_mfma_f32_16x16x32_f16(
                        af[mt], bf[nt], acc[mt][nt], 0, 0, 0);
        }
        __syncthreads();
    }
    // epilogue: repack C to fp16 via LDS (C layout: row=q*4+reg, col=r16)
    _Float16 (*eb)[264] = (_Float16(*)[264])smem;
#pragma unroll
    for (int mt = 0; mt < 2; ++mt) {
        const int er = wm * 32 + mt * 16 + q * 4;
#pragma unroll
        for (int reg = 0; reg < 4; ++reg)
#pragma unroll
            for (int nt = 0; nt < 8; ++nt)
                eb[er + reg][wn * 128 + nt * 16 + r16] = (_Float16)acc[mt][nt][reg];
    }
    __syncthreads();
    const int r = tid >> 2, qq = tid & 3;    // qq: 64-col quarter -> (layer, head)
    const int grow = row0 + r;
    if (grow < n) {
        const int l2 = qq >> 1;
        const int hh = qq & 1;
        const float* avS = &attv[l2 * 2 + 0][hh * 64];
        const float* avD = &attv[l2 * 2 + 1][hh * 64];
        _Float16* hout = h16 + (size_t)l2 * NN * HCH + (size_t)grow * HCH + hh * 64;
        float ds = 0.f, dd = 0.f;
#pragma unroll
        for (int i = 0; i < 8; ++i) {
            half8v v = *(half8v*)&eb[r][qq * 64 + i * 8];
            *(half8v*)(hout + i * 8) = v;
#pragma unroll
            for (int j = 0; j < 8; ++j) {
                float f = (float)v[j];
                ds = fmaf(f, avS[i * 8 + j], ds);
                dd = fmaf(f, avD[i * 8 + j], dd);
            }
        }
        a_s[(size_t)l2 * 2 * NN + 2 * grow + hh] = ds;
        a_d[(size_t)l2 * 2 * NN + 2 * grow + hh] = dd;
    }
}

// =================== AGG+FC fused ===========================================
// 6250 blocks x 16 nodes. Each wave: 4 nodes x 2 layers (softmax-aggregate,
// relu+bias -> xc row in LDS), then the block finishes with an MFMA
// out[16 x 64] = xcs[16 x 256] @ fcW + fcb. xc16 never touches HBM.
__global__ __launch_bounds__(256) void agg_fc(
    const _Float16* __restrict__ h16, const float2* __restrict__ a_s,
    const float2* __restrict__ a_d, const int* __restrict__ gstart,
    const int* __restrict__ gend, const int* __restrict__ bstore,
    const float* __restrict__ bias0, const float* __restrict__ bias1,
    const _Float16* __restrict__ fw2, const float* __restrict__ fcb,
    float* __restrict__ out, int n)
{
    __shared__ __align__(16) uint2 sh[4][64];        // [wave][slot]: {src, half2 p}
    __shared__ __align__(16) _Float16 xcs[16][264];  // block's 16 concat xc rows
    const int tid = threadIdx.x;
    const int wid = tid >> 6, lane = tid & 63;
    const int wbase = blockIdx.x * 16 + wid * 4;
    const int cl = lane & 15;         // column group: cols 8*cl .. 8*cl+7
    const int w2 = lane >> 4;         // edge-pair sub-slot 0..3
    const int hh = cl >> 3;           // head for these columns
    const u32 psel = hh ? 0x07060302u : 0x05040100u;
    const fp16x2 one2 = { (__fp16)1.f, (__fp16)1.f };

    float bv[2][8];
#pragma unroll
    for (int j = 0; j < 8; ++j) {
        bv[0][j] = bias0[cl * 8 + j];
        bv[1][j] = bias1[cl * 8 + j];
    }

    for (int ni = 0; ni < 4; ++ni) {
        const int node = wbase + ni;
        const bool valid = node < n;
        const int nn = valid ? node : 0;
        const int xr = wid * 4 + ni;
        for (int lay = 0; lay < 2; ++lay) {
            const _Float16* hL = h16 + (size_t)lay * NN * HCH;
            const float2* asL = a_s + (size_t)lay * NN;
            const float2* adL = a_d + (size_t)lay * NN;
            const int* ssort = bstore + (size_t)lay * NB * CAP;
            int start = gstart[(size_t)lay * NN + nn];
            int end = gend[(size_t)lay * NN + nn];
            start = start < 0 ? 0 : (start > NB * CAP ? NB * CAP : start);
            end = end < start ? start : (end > NB * CAP ? NB * CAP : end);
            const float2 ad = adL[nn];
            const float2 asn = asL[nn];

            float acc[8] = {0.f, 0.f, 0.f, 0.f, 0.f, 0.f, 0.f, 0.f};
            float den = 0.f;

            for (int base2 = start; base2 < end; base2 += 64) {
                const int j = base2 + lane;
                const int cnt = min(64, end - base2);
                float p0 = 0.f, p1 = 0.f;
                int s = 0;
                if (j < end) {
                    s = ssort[j];
                    if ((unsigned)s >= (unsigned)n) s = 0;   // poison guard
                    float2 a = asL[s];
                    p0 = __expf(lrelu(a.x + ad.x));
                    p1 = __expf(lrelu(a.y + ad.y));
                }
                H2U pk; pk.h = __builtin_amdgcn_cvt_pkrtz(p0, p1);
                sh[wid][lane] = make_uint2((u32)s, pk.u);
                __builtin_amdgcn_wave_barrier();
                const int cnt8 = (cnt + 7) & ~7;
                for (int t = 0; t < cnt8; t += 8) {
                    const uint4 rec = *(const uint4*)&sh[wid][t + 2 * w2];
                    H2U pph; pph.u = __builtin_amdgcn_perm(rec.w, rec.y, psel);
                    const half8v hv0 = *(const half8v*)(hL + ((rec.x << 7) | (u32)(cl << 3)));
                    const half8v hv1 = *(const half8v*)(hL + ((rec.z << 7) | (u32)(cl << 3)));
                    const u32* ap = (const u32*)&hv0;
                    const u32* bp = (const u32*)&hv1;
#pragma unroll
                    for (int d2 = 0; d2 < 4; ++d2) {
                        H2U pe, po;
                        pe.u = __builtin_amdgcn_perm(bp[d2], ap[d2], 0x05040100u);
                        po.u = __builtin_amdgcn_perm(bp[d2], ap[d2], 0x07060302u);
                        acc[2 * d2]     = __builtin_amdgcn_fdot2(pe.h, pph.h, acc[2 * d2], false);
                        acc[2 * d2 + 1] = __builtin_amdgcn_fdot2(po.h, pph.h, acc[2 * d2 + 1], false);
                    }
                    den = __builtin_amdgcn_fdot2(pph.h, one2, den, false);
                }
                __builtin_amdgcn_wave_barrier();
            }
            // self loop (w2==0 group only, so it is counted once after the reduce)
            const float ps0 = __expf(lrelu(asn.x + ad.x));
            const float ps1 = __expf(lrelu(asn.y + ad.y));
            if (w2 == 0) {
                const half8v hv = *(const half8v*)(hL + (((u32)nn << 7) | (u32)(cl << 3)));
                const float pl = hh ? ps1 : ps0;
#pragma unroll
                for (int j2 = 0; j2 < 8; ++j2)
                    acc[j2] = fmaf(pl, (float)hv[j2], acc[j2]);
                den += pl;
            }
            // combine the 4 edge-pair sub-slots (numerators + denominator)
#pragma unroll
            for (int j2 = 0; j2 < 8; ++j2) {
                acc[j2] += __shfl_xor(acc[j2], 16, 64);
                acc[j2] += __shfl_xor(acc[j2], 32, 64);
            }
            den += __shfl_xor(den, 16, 64);
            den += __shfl_xor(den, 32, 64);
            if (lane < 16) {
                const float inv = 1.f / den;
                half8v o;
#pragma unroll
                for (int j2 = 0; j2 < 8; ++j2)
                    o[j2] = (_Float16)fmaxf(acc[j2] * inv + bv[lay][j2], 0.f);
                *(half8v*)&xcs[xr][lay * HCH + cl * 8] = o;
            }
        }
    }
    __syncthreads();

    // ---- FC epilogue: out[16 x 64] = xcs @ fcW + fcb (8 MFMAs per wave) ----
    const int q = lane >> 4, r16 = lane & 15;
    float4v facc = (float4v){0.f, 0.f, 0.f, 0.f};
#pragma unroll
    for (int s = 0; s < 8; ++s) {
        const half8v af = *(half8v*)&xcs[r16][s * 32 + q * 8];
        const half8v bf =
            *(const half8v*)(fw2 + (size_t)(wid * 16 + r16) * 256 + s * 32 + q * 8);
        facc = __builtin_amdgcn_mfma_f32_16x16x32_f16(af, bf, facc, 0, 0, 0);
    }
    const int col = wid * 16 + r16;
    const float fb = fcb[col];
#pragma unroll
    for (int reg = 0; reg < 4; ++reg) {
        const int grow = blockIdx.x * 16 + q * 4 + reg;
        if (grow < n)
            out[(size_t)grow * OUT_DIM + col] = facc[reg] + fb;
    }
}

// ---------------- launch ----------------
extern "C" void kernel_launch(void* const* d_in, const int* in_sizes, int n_in,
                              void* d_out, int out_size, void* d_ws, size_t ws_size,
                              hipStream_t stream)
{
    const float* x = (const float*)d_in[0];
    const int* ei[2] = { (const int*)d_in[1], (const int*)d_in[2] };
    const float* W[2] = { (const float*)d_in[3], (const float*)d_in[7] };
    const float* attS[2] = { (const float*)d_in[4], (const float*)d_in[8] };
    const float* attD[2] = { (const float*)d_in[5], (const float*)d_in[9] };
    const float* bias[2] = { (const float*)d_in[6], (const float*)d_in[10] };
    const float* fcW = (const float*)d_in[11];
    const float* fcb = (const float*)d_in[12];
    float* out = (float*)d_out;

    char* p = (char*)d_ws;
    size_t need = 0;
    auto carve = [&](size_t bytes) {
        char* r = p;
        size_t b = (bytes + 255) & ~(size_t)255;
        p += b;
        need += b;
        return r;
    };
    _Float16* h16 = (_Float16*)carve((size_t)2 * NN * HCH * 2);    // both layers
    _Float16* wt = (_Float16*)carve((size_t)2 * IN_DIM * HCH * 2);
    _Float16* fcw2 = (_Float16*)carve((size_t)256 * OUT_DIM * 2);
    float* a_s = (float*)carve((size_t)2 * NN * 8);                // [layer][node][head]
    float* a_d = (float*)carve((size_t)2 * NN * 8);
    int* gcursor = (int*)carve((size_t)2 * NB * 4);
    int* bstore = (int*)carve((size_t)2 * NB * CAP * 4);
    int* gstart = (int*)carve((size_t)2 * NN * 4);
    int* gend = (int*)carve((size_t)2 * NN * 4);
    if (need > ws_size) return;  // loud correctness failure instead of OOB crash

    (void)hipMemsetAsync(gcursor, 0, (size_t)2 * NB * 4, stream);

    // convw || bucket (independent)
    prep_kernel<<<CONV_BLOCKS + 2 * BUCKET_PER_LAYER, 256, 0, stream>>>(
        W[0], W[1], fcW, wt, fcw2, ei[0], ei[1], gcursor, bstore);

    // gemm || sort (independent; interleaved roles)
    mid_kernel<<<GEMM_BLOCKS + SORT_BLOCKS, 256, 0, stream>>>(
        x, wt, attS[0], attD[0], attS[1], attD[1],
        h16, a_s, a_d, gcursor, bstore, gstart, gend, NN);

    // agg (both layers per node) + fused FC
    agg_fc<<<(NN + 15) / 16, 256, 0, stream>>>(
        h16, (const float2*)a_s, (const float2*)a_d,
        gstart, gend, bstore, bias[0], bias[1], fcw2, fcb, out, NN);
}

// Round 5
// 468.647 us; speedup vs baseline: 1.0214x; 1.0214x over previous
//
#include <hip/hip_runtime.h>
#include <hip/hip_fp16.h>
#include <math.h>

#define NN 100000
#define IN_DIM 256
#define HCH 128      // HEADS*HID
#define OUT_DIM 64
#define EE 1600000
#define NEG_SLOPE 0.2f

#define NB 1024      // dst buckets per layer
#define NPB 98       // nodes per bucket (1024*98 >= 100000)
#define CAP 2048     // bucket capacity (mean 1562, std ~40 -> 12 sigma margin)

#define GEMM_BLOCKS 1563     // (NN+63)/64
#define CONV_BLOCKS 320      // (2*256*128 + 256*64)/256
#define BUCKET_PER_LAYER 512 // 512 blocks x 3125 edges
#define SORT_BLOCKS (2 * NB)

typedef _Float16 half8v __attribute__((ext_vector_type(8)));
typedef _Float16 half4v __attribute__((ext_vector_type(4)));
typedef __fp16 fp16x2 __attribute__((ext_vector_type(2)));   // clang builtin half2 type
typedef float float4v __attribute__((ext_vector_type(4)));
typedef unsigned int u32;

union H2U { u32 u; fp16x2 h; };

__device__ __forceinline__ float lrelu(float v) { return v > 0.f ? v : NEG_SLOPE * v; }

// =================== PREP: convw (blocks 0..319)  ||  bucket (1024 blocks) ==
__global__ __launch_bounds__(256, 8) void prep_kernel(
    const float* __restrict__ W0, const float* __restrict__ W1,
    const float* __restrict__ fcW,
    _Float16* __restrict__ wt, _Float16* __restrict__ fcw2,
    const int* __restrict__ ei0, const int* __restrict__ ei1,
    int* __restrict__ gcursor, int* __restrict__ bstore)
{
    __shared__ int hist[NB];
    __shared__ int base[NB];
    const int tid = threadIdx.x;

    if (blockIdx.x < CONV_BLOCKS) {
        int i = blockIdx.x * 256 + tid;
        if (i < 2 * IN_DIM * HCH) {
            int l = i >> 15, rem = i & 32767;
            int c = rem >> 8, k = rem & 255;
            const float* W = l ? W1 : W0;
            wt[i] = (_Float16)W[(size_t)k * HCH + c];
            return;
        }
        int j = i - 2 * IN_DIM * HCH;
        if (j < 256 * OUT_DIM) {
            int c = j >> 8, k = j & 255;   // fcw2[c*256 + k] = fcW[k][c]
            fcw2[j] = (_Float16)fcW[(size_t)k * OUT_DIM + c];
        }
        return;
    }

    // ---- bucket role ----
    const int bb = blockIdx.x - CONV_BLOCKS;       // 0..1023
    const int lay = bb >> 9;                       // 512 blocks per layer
    const int idx = bb & 511;
    const int* src = lay ? ei1 : ei0;
    const int* dst = src + EE;
    int* gcur = gcursor + lay * NB;
    int* bst = bstore + (size_t)lay * NB * CAP;

    const int per = (EE + BUCKET_PER_LAYER - 1) / BUCKET_PER_LAYER;  // 3125
    const int e0 = idx * per;
    const int e1 = min(EE, e0 + per);
    for (int i = tid; i < NB; i += 256) hist[i] = 0;
    __syncthreads();
    for (int i = e0 + tid; i < e1; i += 256)
        atomicAdd(&hist[dst[i] / NPB], 1);
    __syncthreads();
    for (int b = tid; b < NB; b += 256) {
        int c = hist[b];
        base[b] = c ? atomicAdd(&gcur[b], c) : 0;
        hist[b] = 0;
    }
    __syncthreads();
    for (int i = e0 + tid; i < e1; i += 256) {
        int d = dst[i];
        int s = src[i];
        int b = d / NPB;
        int pos = base[b] + atomicAdd(&hist[b], 1);
        if (pos >= 0 && pos < CAP) bst[b * CAP + pos] = (s << 7) | (d - b * NPB);
    }
}

// =================== MID: gemm (1563 blocks)  ||  sort (2048 blocks) ========
__global__ __launch_bounds__(256, 3) void mid_kernel(
    const float* __restrict__ x, const _Float16* __restrict__ wt,
    const float* __restrict__ attS0, const float* __restrict__ attD0,
    const float* __restrict__ attS1, const float* __restrict__ attD1,
    _Float16* __restrict__ h16, float* __restrict__ a_s, float* __restrict__ a_d,
    const int* __restrict__ gcursor, int* __restrict__ bstore,
    int* __restrict__ gstart, int* __restrict__ gend, int n)
{
    __shared__ __align__(16) _Float16 smem[64 * 72 + 256 * 72];  // 46.1 KB
    __shared__ float attv[4][128];
    const int tid = threadIdx.x;

    const long long TS = SORT_BLOCKS;                  // 2048
    const long long TB = GEMM_BLOCKS + SORT_BLOCKS;    // 3611
    const int k = blockIdx.x;
    const int slo = (int)(((long long)k * TS) / TB);
    const int shi = (int)(((long long)(k + 1) * TS) / TB);

    if (shi > slo) {
        // ---- sort role: per-bucket LDS counting sort (in place) ----
        int* raw = (int*)smem;
        int* sorted = raw + CAP;
        int* curs = sorted + CAP;
        int* scanbuf = curs + 128;
        const int sb = slo;                  // 0..2047
        const int lay = sb >> 10;
        const int b = sb & (NB - 1);
        const int* gcur = gcursor + lay * NB;
        int* bst = bstore + (size_t)lay * NB * CAP;
        int* gs = gstart + (size_t)lay * NN;
        int* ge = gend + (size_t)lay * NN;

        const int node0 = b * NPB;
        const int nnode = min(NPB, n - node0);
        if (nnode <= 0) return;
        int cnt = gcur[b];
        cnt = cnt < 0 ? 0 : (cnt > CAP ? CAP : cnt);

        for (int i = tid; i < cnt; i += 256) raw[i] = bst[b * CAP + i];
        if (tid < 128) curs[tid] = 0;
        __syncthreads();
        for (int i = tid; i < cnt; i += 256) atomicAdd(&curs[raw[i] & 127], 1);
        __syncthreads();
        if (tid < 128) scanbuf[tid] = curs[tid];
        __syncthreads();
        for (int off = 1; off < 128; off <<= 1) {
            int v = 0;
            if (tid < 128) { v = scanbuf[tid]; if (tid >= off) v += scanbuf[tid - off]; }
            __syncthreads();
            if (tid < 128) scanbuf[tid] = v;
            __syncthreads();
        }
        if (tid < 128) {
            int ex = tid ? scanbuf[tid - 1] : 0;
            curs[tid] = ex;
            if (tid < nnode) {
                gs[node0 + tid] = b * CAP + ex;
                ge[node0 + tid] = b * CAP + scanbuf[tid];
            }
        }
        __syncthreads();
        for (int i = tid; i < cnt; i += 256) {
            int item = raw[i];
            int pos = atomicAdd(&curs[item & 127], 1);
            if (pos >= 0 && pos < CAP) sorted[pos] = item >> 7;
        }
        __syncthreads();
        for (int i = tid; i < cnt; i += 256) bst[b * CAP + i] = sorted[i];
        return;
    }

    // ---- gemm role: fused dual-layer GEMM + attention-score epilogue ----
    _Float16 (*As)[72] = (_Float16(*)[72])smem;
    _Float16 (*Bs)[72] = (_Float16(*)[72])(smem + 64 * 72);
    const int gb = k - slo;                  // 0..1562
    const int lane = tid & 63, wave = tid >> 6;
    const int wm = wave & 1, wn = wave >> 1;
    const int q = lane >> 4, r16 = lane & 15;
    const int row0 = gb * 64;

    if (tid < 128) {
        attv[0][tid] = attS0[tid]; attv[1][tid] = attD0[tid];
        attv[2][tid] = attS1[tid]; attv[3][tid] = attD1[tid];
    }

    float4v acc[2][8];
#pragma unroll
    for (int i = 0; i < 2; ++i)
#pragma unroll
        for (int j = 0; j < 8; ++j) acc[i][j] = (float4v){0.f, 0.f, 0.f, 0.f};

    const int ar = tid >> 2, aq = tid & 3;   // A: row, k-quarter (16 floats)
    const bool rok = (row0 + ar) < n;
    for (int kt = 0; kt < IN_DIM; kt += 64) {
        const float* xp = x + (size_t)(row0 + ar) * IN_DIM + kt + aq * 16;
#pragma unroll
        for (int i = 0; i < 4; ++i) {
            float4 v = rok ? *(const float4*)(xp + i * 4) : make_float4(0.f, 0.f, 0.f, 0.f);
            half4v hv = { (_Float16)v.x, (_Float16)v.y, (_Float16)v.z, (_Float16)v.w };
            *(half4v*)&As[ar][aq * 16 + i * 4] = hv;
        }
        const _Float16* wp = wt + (size_t)tid * IN_DIM + kt;
#pragma unroll
        for (int i = 0; i < 8; ++i)
            *(half8v*)&Bs[tid][i * 8] = *(const half8v*)(wp + i * 8);
        __syncthreads();
#pragma unroll
        for (int s = 0; s < 2; ++s) {
            half8v af[2], bf[8];
#pragma unroll
            for (int t = 0; t < 2; ++t)
                af[t] = *(half8v*)&As[wm * 32 + t * 16 + r16][s * 32 + q * 8];
#pragma unroll
            for (int t = 0; t < 8; ++t)
                bf[t] = *(half8v*)&Bs[wn * 128 + t * 16 + r16][s * 32 + q * 8];
#pragma unroll
            for (int mt = 0; mt < 2; ++mt)
#pragma unroll
                for (int nt = 0; nt < 8; ++nt)
                    acc[mt][nt] = __builtin_amdgcn_mfma_f32_16x16x32_f16(
                        af[mt], bf[nt], acc[mt][nt], 0, 0, 0);
        }
        __syncthreads();
    }
    // epilogue: repack C to fp16 via LDS (C layout: row=q*4+reg, col=r16)
    _Float16 (*eb)[264] = (_Float16(*)[264])smem;
#pragma unroll
    for (int mt = 0; mt < 2; ++mt) {
        const int er = wm * 32 + mt * 16 + q * 4;
#pragma unroll
        for (int reg = 0; reg < 4; ++reg)
#pragma unroll
            for (int nt = 0; nt < 8; ++nt)
                eb[er + reg][wn * 128 + nt * 16 + r16] = (_Float16)acc[mt][nt][reg];
    }
    __syncthreads();
    const int r = tid >> 2, qq = tid & 3;    // qq: 64-col quarter -> (layer, head)
    const int grow = row0 + r;
    if (grow < n) {
        const int l2 = qq >> 1;
        const int hh = qq & 1;
        const float* avS = &attv[l2 * 2 + 0][hh * 64];
        const float* avD = &attv[l2 * 2 + 1][hh * 64];
        _Float16* hout = h16 + (size_t)l2 * NN * HCH + (size_t)grow * HCH + hh * 64;
        float ds = 0.f, dd = 0.f;
#pragma unroll
        for (int i = 0; i < 8; ++i) {
            half8v v = *(half8v*)&eb[r][qq * 64 + i * 8];
            *(half8v*)(hout + i * 8) = v;
#pragma unroll
            for (int j = 0; j < 8; ++j) {
                float f = (float)v[j];
                ds = fmaf(f, avS[i * 8 + j], ds);
                dd = fmaf(f, avD[i * 8 + j], dd);
            }
        }
        a_s[(size_t)l2 * 2 * NN + 2 * grow + hh] = ds;
        a_d[(size_t)l2 * 2 * NN + 2 * grow + hh] = dd;
    }
}

// =================== AGG: group-parallel nodes ==============================
// grid (6250, 2). Each 16-lane group owns ONE node: lane i covers cols
// 8i..8i+7 AND stages edge slot i. No cross-group reduces: each lane
// accumulates all of its node's edges for its columns, and den falls out of
// the per-lane fdot2 stream (every lane sees every edge pair of its node).
__global__ __launch_bounds__(256) void agg_kernel(
    const _Float16* __restrict__ h16, const float2* __restrict__ a_s,
    const float2* __restrict__ a_d, const int* __restrict__ gstart,
    const int* __restrict__ gend, const int* __restrict__ bstore,
    const float* __restrict__ bias0, const float* __restrict__ bias1,
    _Float16* __restrict__ xc16, int n)
{
    __shared__ __align__(16) uint2 sh[4][64];   // [wave][group*16+slot]
    const int lay = blockIdx.y;
    const _Float16* hL = h16 + (size_t)lay * NN * HCH;
    const float2* asL = a_s + (size_t)lay * NN;
    const float2* adL = a_d + (size_t)lay * NN;
    const int* gsL = gstart + (size_t)lay * NN;
    const int* geL = gend + (size_t)lay * NN;
    const int* ssort = bstore + (size_t)lay * NB * CAP;
    const float* bias = lay ? bias1 : bias0;

    const int wid = threadIdx.x >> 6, lane = threadIdx.x & 63;
    const int g = lane >> 4;          // group: which of the wave's 4 nodes
    const int i = lane & 15;          // lane-in-group: col group AND stage slot
    const int hh = i >> 3;            // head for these columns
    const u32 psel = hh ? 0x07060302u : 0x05040100u;
    const fp16x2 one2 = { (__fp16)1.f, (__fp16)1.f };

    const int node = blockIdx.x * 16 + wid * 4 + g;
    const bool valid = node < n;
    const int nn = valid ? node : 0;

    float bv[8];
#pragma unroll
    for (int j = 0; j < 8; ++j) bv[j] = bias[i * 8 + j];

    int start = gsL[nn], end = geL[nn];
    start = start < 0 ? 0 : (start > NB * CAP ? NB * CAP : start);
    end = end < start ? start : (end > NB * CAP ? NB * CAP : end);
    const int cnt = end - start;
    const float2 ad = adL[nn];
    const float2 asn = asL[nn];

    float acc[8] = {0.f, 0.f, 0.f, 0.f, 0.f, 0.f, 0.f, 0.f};
    float den = 0.f;
    uint2* slots = &sh[wid][g * 16];

    for (int base = 0; base < cnt; base += 16) {
        const int idx = start + base + i;
        float p0 = 0.f, p1 = 0.f;
        int s = 0;
        if (idx < end) {
            s = ssort[idx];
            if ((unsigned)s >= (unsigned)n) s = 0;   // poison guard
            float2 a = asL[s];
            p0 = __expf(lrelu(a.x + ad.x));
            p1 = __expf(lrelu(a.y + ad.y));
        }
        H2U pk; pk.h = __builtin_amdgcn_cvt_pkrtz(p0, p1);
        slots[i] = make_uint2((u32)s, pk.u);
        __builtin_amdgcn_wave_barrier();
        const int c2 = min(16, cnt - base);
        for (int t = 0; t < c2; t += 2) {
            const uint4 rec = *(const uint4*)&slots[t];   // slots t, t+1
            H2U pph; pph.u = __builtin_amdgcn_perm(rec.w, rec.y, psel);
            const half8v hv0 = *(const half8v*)(hL + ((rec.x << 7) | (u32)(i << 3)));
            const half8v hv1 = *(const half8v*)(hL + ((rec.z << 7) | (u32)(i << 3)));
            const u32* ap = (const u32*)&hv0;
            const u32* bp = (const u32*)&hv1;
#pragma unroll
            for (int d2 = 0; d2 < 4; ++d2) {
                H2U pe, po;
                pe.u = __builtin_amdgcn_perm(bp[d2], ap[d2], 0x05040100u);
                po.u = __builtin_amdgcn_perm(bp[d2], ap[d2], 0x07060302u);
                acc[2 * d2]     = __builtin_amdgcn_fdot2(pe.h, pph.h, acc[2 * d2], false);
                acc[2 * d2 + 1] = __builtin_amdgcn_fdot2(po.h, pph.h, acc[2 * d2 + 1], false);
            }
            den = __builtin_amdgcn_fdot2(pph.h, one2, den, false);
        }
        __builtin_amdgcn_wave_barrier();
    }
    // self loop (parallel across groups; no reduce anywhere)
    {
        const float ps0 = __expf(lrelu(asn.x + ad.x));
        const float ps1 = __expf(lrelu(asn.y + ad.y));
        const half8v hv = *(const half8v*)(hL + (((u32)nn << 7) | (u32)(i << 3)));
        const float pl = hh ? ps1 : ps0;
#pragma unroll
        for (int j2 = 0; j2 < 8; ++j2)
            acc[j2] = fmaf(pl, (float)hv[j2], acc[j2]);
        den += pl;
    }
    if (valid) {
        const float inv = 1.f / den;
        half8v o;
#pragma unroll
        for (int j2 = 0; j2 < 8; ++j2)
            o[j2] = (_Float16)fmaxf(acc[j2] * inv + bv[j2], 0.f);
        *(half8v*)(xc16 + (size_t)node * 256 + lay * HCH + i * 8) = o;
    }
}

// ---------------- FC via MFMA, K=256 concat: out = [xc0|xc1] @ fcW + fcb ----
__global__ __launch_bounds__(256) void fc_mfma(const _Float16* __restrict__ xc16,
                                               const _Float16* __restrict__ fw2,
                                               const float* __restrict__ fcb,
                                               float* __restrict__ out, int n)
{
    __shared__ _Float16 axs[64][264];
    const int tid = threadIdx.x;
    const int lane = tid & 63, wave = tid >> 6;
    const int q = lane >> 4, r16 = lane & 15;
    const int row0 = blockIdx.x * 64;

    // stage A: 64 rows x 256 k (8 half8 loads/thread, coalesced)
#pragma unroll
    for (int i = 0; i < 8; ++i) {
        const int idx = i * 256 + tid;
        const int row = idx >> 5;
        const int kg = (idx & 31) * 8;
        half8v v = { 0, 0, 0, 0, 0, 0, 0, 0 };
        if (row0 + row < n)
            v = *(const half8v*)(xc16 + (size_t)(row0 + row) * 256 + kg);
        *(half8v*)&axs[row][kg] = v;
    }
    __syncthreads();

    float4v acc[4];
#pragma unroll
    for (int i = 0; i < 4; ++i) acc[i] = (float4v){0.f, 0.f, 0.f, 0.f};
#pragma unroll
    for (int s = 0; s < 8; ++s) {
        const half8v af = *(half8v*)&axs[wave * 16 + r16][s * 32 + q * 8];
#pragma unroll
        for (int nt = 0; nt < 4; ++nt) {
            const half8v bf =
                *(const half8v*)(fw2 + (size_t)(nt * 16 + r16) * 256 + s * 32 + q * 8);
            acc[nt] = __builtin_amdgcn_mfma_f32_16x16x32_f16(af, bf, acc[nt], 0, 0, 0);
        }
    }
#pragma unroll
    for (int nt = 0; nt < 4; ++nt) {
        const int col = nt * 16 + r16;
#pragma unroll
        for (int reg = 0; reg < 4; ++reg) {
            const int row = row0 + wave * 16 + q * 4 + reg;
            if (row < n)
                out[(size_t)row * OUT_DIM + col] = acc[nt][reg] + fcb[col];
        }
    }
}

// ---------------- launch ----------------
extern "C" void kernel_launch(void* const* d_in, const int* in_sizes, int n_in,
                              void* d_out, int out_size, void* d_ws, size_t ws_size,
                              hipStream_t stream)
{
    const float* x = (const float*)d_in[0];
    const int* ei[2] = { (const int*)d_in[1], (const int*)d_in[2] };
    const float* W[2] = { (const float*)d_in[3], (const float*)d_in[7] };
    const float* attS[2] = { (const float*)d_in[4], (const float*)d_in[8] };
    const float* attD[2] = { (const float*)d_in[5], (const float*)d_in[9] };
    const float* bias[2] = { (const float*)d_in[6], (const float*)d_in[10] };
    const float* fcW = (const float*)d_in[11];
    const float* fcb = (const float*)d_in[12];
    float* out = (float*)d_out;

    char* p = (char*)d_ws;
    size_t need = 0;
    auto carve = [&](size_t bytes) {
        char* r = p;
        size_t b = (bytes + 255) & ~(size_t)255;
        p += b;
        need += b;
        return r;
    };
    _Float16* h16 = (_Float16*)carve((size_t)2 * NN * HCH * 2);    // both layers
    _Float16* xc16 = (_Float16*)carve((size_t)NN * 256 * 2);       // concat rows
    _Float16* wt = (_Float16*)carve((size_t)2 * IN_DIM * HCH * 2);
    _Float16* fcw2 = (_Float16*)carve((size_t)256 * OUT_DIM * 2);
    float* a_s = (float*)carve((size_t)2 * NN * 8);                // [layer][node][head]
    float* a_d = (float*)carve((size_t)2 * NN * 8);
    int* gcursor = (int*)carve((size_t)2 * NB * 4);
    int* bstore = (int*)carve((size_t)2 * NB * CAP * 4);
    int* gstart = (int*)carve((size_t)2 * NN * 4);
    int* gend = (int*)carve((size_t)2 * NN * 4);
    if (need > ws_size) return;  // loud correctness failure instead of OOB crash

    (void)hipMemsetAsync(gcursor, 0, (size_t)2 * NB * 4, stream);

    // convw || bucket (independent)
    prep_kernel<<<CONV_BLOCKS + 2 * BUCKET_PER_LAYER, 256, 0, stream>>>(
        W[0], W[1], fcW, wt, fcw2, ei[0], ei[1], gcursor, bstore);

    // gemm || sort (independent; interleaved roles)
    mid_kernel<<<GEMM_BLOCKS + SORT_BLOCKS, 256, 0, stream>>>(
        x, wt, attS[0], attD[0], attS[1], attD[1],
        h16, a_s, a_d, gcursor, bstore, gstart, gend, NN);

    // agg: group-parallel nodes, both layers via grid.y
    agg_kernel<<<dim3((NN + 15) / 16, 2), 256, 0, stream>>>(
        h16, (const float2*)a_s, (const float2*)a_d,
        gstart, gend, bstore, bias[0], bias[1], xc16, NN);

    // FC: out = [xc0|xc1] @ fcW + fcb
    fc_mfma<<<GEMM_BLOCKS, 256, 0, stream>>>(xc16, fcw2, fcb, out, NN);
}

// Round 6
// 458.025 us; speedup vs baseline: 1.0451x; 1.0232x over previous
//
#include <hip/hip_runtime.h>
#include <hip/hip_fp16.h>
#include <math.h>

#define NN 100000
#define IN_DIM 256
#define HCH 128      // HEADS*HID
#define OUT_DIM 64
#define EE 1600000
#define NEG_SLOPE 0.2f

#define NB 1024      // dst buckets per layer
#define NPB 98       // nodes per bucket (1024*98 >= 100000)
#define CAP 2048     // bucket capacity (mean 1562, std ~40 -> 12 sigma margin)

#define GEMM_BLOCKS 1563     // (NN+63)/64
#define CONV_BLOCKS 320      // (2*256*128 + 256*64)/256
#define BUCKET_PER_LAYER 512 // 512 blocks x 3125 edges
#define BUCKET_BLOCKS (2 * BUCKET_PER_LAYER)
#define WORK_BLOCKS (GEMM_BLOCKS + BUCKET_BLOCKS)   // 2587
#define AGG_X ((NN + 15) / 16)                      // 6250

typedef _Float16 half8v __attribute__((ext_vector_type(8)));
typedef _Float16 half4v __attribute__((ext_vector_type(4)));
typedef __fp16 fp16x2 __attribute__((ext_vector_type(2)));   // clang builtin half2 type
typedef float float4v __attribute__((ext_vector_type(4)));
typedef unsigned int u32;

union H2U { u32 u; fp16x2 h; };

__device__ __forceinline__ float lrelu(float v) { return v > 0.f ? v : NEG_SLOPE * v; }

// =================== K0: convw + gcursor zero ===============================
__global__ __launch_bounds__(256) void conv_kernel(
    const float* __restrict__ W0, const float* __restrict__ W1,
    const float* __restrict__ fcW,
    _Float16* __restrict__ wt, _Float16* __restrict__ fcw2,
    int* __restrict__ gcursor)
{
    const int tid = threadIdx.x;
    if (blockIdx.x == CONV_BLOCKS) {
        for (int i = tid; i < 2 * NB; i += 256) gcursor[i] = 0;
        return;
    }
    int i = blockIdx.x * 256 + tid;
    if (i < 2 * IN_DIM * HCH) {
        int l = i >> 15, rem = i & 32767;
        int c = rem >> 8, k = rem & 255;
        const float* W = l ? W1 : W0;
        wt[i] = (_Float16)W[(size_t)k * HCH + c];
        return;
    }
    int j = i - 2 * IN_DIM * HCH;
    if (j < 256 * OUT_DIM) {
        int c = j >> 8, k = j & 255;   // fcw2[c*256 + k] = fcW[k][c]
        fcw2[j] = (_Float16)fcW[(size_t)k * OUT_DIM + c];
    }
}

// =================== K1: gemm (1563)  ||  bucket (1024) =====================
// The two whales: gemm is MFMA/VALU-bound, bucket is scatter/BW-bound --
// complementary pipes, co-resident via multiplicative interleave.
// gemm: BK=32, smem 33.8 KB -> 4 blocks/CU.
__global__ __launch_bounds__(256, 4) void work_kernel(
    const float* __restrict__ x, const _Float16* __restrict__ wt,
    const float* __restrict__ attS0, const float* __restrict__ attD0,
    const float* __restrict__ attS1, const float* __restrict__ attD1,
    _Float16* __restrict__ h16, float* __restrict__ a_s, float* __restrict__ a_d,
    const int* __restrict__ ei0, const int* __restrict__ ei1,
    int* __restrict__ gcursor, int* __restrict__ bstore, int n)
{
    __shared__ __align__(16) _Float16 smem[64 * 264];   // 33.8 KB (epilogue max)
    __shared__ float attv[4][128];
    const int tid = threadIdx.x;

    const long long TS = BUCKET_BLOCKS;                // 1024
    const long long TB = WORK_BLOCKS;                  // 2587
    const int k = blockIdx.x;
    const int slo = (int)(((long long)k * TS) / TB);
    const int shi = (int)(((long long)(k + 1) * TS) / TB);

    if (shi > slo) {
        // ---- bucket role ----
        int* hist = (int*)smem;
        int* base = hist + NB;
        const int bb = slo;                            // 0..1023
        const int lay = bb >> 9;
        const int idx = bb & 511;
        const int* src = lay ? ei1 : ei0;
        const int* dst = src + EE;
        int* gcur = gcursor + lay * NB;
        int* bst = bstore + (size_t)lay * NB * CAP;

        const int per = (EE + BUCKET_PER_LAYER - 1) / BUCKET_PER_LAYER;  // 3125
        const int e0 = idx * per;
        const int e1 = min(EE, e0 + per);
        for (int i = tid; i < NB; i += 256) hist[i] = 0;
        __syncthreads();
        for (int i = e0 + tid; i < e1; i += 256)
            atomicAdd(&hist[dst[i] / NPB], 1);
        __syncthreads();
        for (int b = tid; b < NB; b += 256) {
            int c = hist[b];
            base[b] = c ? atomicAdd(&gcur[b], c) : 0;
            hist[b] = 0;
        }
        __syncthreads();
        for (int i = e0 + tid; i < e1; i += 256) {
            int d = dst[i];
            int s = src[i];
            int b = d / NPB;
            int pos = base[b] + atomicAdd(&hist[b], 1);
            if (pos >= 0 && pos < CAP) bst[b * CAP + pos] = (s << 7) | (d - b * NPB);
        }
        return;
    }

    // ---- gemm role: fused dual-layer GEMM + attention-score epilogue ----
    _Float16 (*As)[40] = (_Float16(*)[40])smem;                 // 64 x 32 (+8 pad)
    _Float16 (*Bs)[40] = (_Float16(*)[40])(smem + 64 * 40);     // 256 x 32 (+8 pad)
    const int gb = k - slo;                  // 0..1562
    const int lane = tid & 63, wave = tid >> 6;
    const int wm = wave & 1, wn = wave >> 1;
    const int q = lane >> 4, r16 = lane & 15;
    const int row0 = gb * 64;

    if (tid < 128) {
        attv[0][tid] = attS0[tid]; attv[1][tid] = attD0[tid];
        attv[2][tid] = attS1[tid]; attv[3][tid] = attD1[tid];
    }

    float4v acc[2][8];
#pragma unroll
    for (int i = 0; i < 2; ++i)
#pragma unroll
        for (int j = 0; j < 8; ++j) acc[i][j] = (float4v){0.f, 0.f, 0.f, 0.f};

    const int ar = tid >> 2, aq = tid & 3;   // A: row, 8-float k-slice
    const bool rok = (row0 + ar) < n;
    for (int kt = 0; kt < IN_DIM; kt += 32) {
        const float* xp = x + (size_t)(row0 + ar) * IN_DIM + kt + aq * 8;
        float4 v0 = rok ? *(const float4*)xp : make_float4(0.f, 0.f, 0.f, 0.f);
        float4 v1 = rok ? *(const float4*)(xp + 4) : make_float4(0.f, 0.f, 0.f, 0.f);
        half8v hv = { (_Float16)v0.x, (_Float16)v0.y, (_Float16)v0.z, (_Float16)v0.w,
                      (_Float16)v1.x, (_Float16)v1.y, (_Float16)v1.z, (_Float16)v1.w };
        *(half8v*)&As[ar][aq * 8] = hv;
        const _Float16* wp = wt + (size_t)tid * IN_DIM + kt;
#pragma unroll
        for (int i = 0; i < 4; ++i)
            *(half8v*)&Bs[tid][i * 8] = *(const half8v*)(wp + i * 8);
        __syncthreads();
        half8v af[2];
#pragma unroll
        for (int t = 0; t < 2; ++t)
            af[t] = *(half8v*)&As[wm * 32 + t * 16 + r16][q * 8];
#pragma unroll
        for (int hf = 0; hf < 2; ++hf) {
            half8v bf[4];
#pragma unroll
            for (int j = 0; j < 4; ++j)
                bf[j] = *(half8v*)&Bs[wn * 128 + (hf * 4 + j) * 16 + r16][q * 8];
#pragma unroll
            for (int mt = 0; mt < 2; ++mt)
#pragma unroll
                for (int j = 0; j < 4; ++j)
                    acc[mt][hf * 4 + j] = __builtin_amdgcn_mfma_f32_16x16x32_f16(
                        af[mt], bf[j], acc[mt][hf * 4 + j], 0, 0, 0);
        }
        __syncthreads();
    }
    // epilogue: repack C to fp16 via LDS (C layout: row=q*4+reg, col=r16)
    _Float16 (*eb)[264] = (_Float16(*)[264])smem;
#pragma unroll
    for (int mt = 0; mt < 2; ++mt) {
        const int er = wm * 32 + mt * 16 + q * 4;
#pragma unroll
        for (int reg = 0; reg < 4; ++reg)
#pragma unroll
            for (int nt = 0; nt < 8; ++nt)
                eb[er + reg][wn * 128 + nt * 16 + r16] = (_Float16)acc[mt][nt][reg];
    }
    __syncthreads();
    const int r = tid >> 2, qq = tid & 3;    // qq: 64-col quarter -> (layer, head)
    const int grow = row0 + r;
    if (grow < n) {
        const int l2 = qq >> 1;
        const int hh = qq & 1;
        const float* avS = &attv[l2 * 2 + 0][hh * 64];
        const float* avD = &attv[l2 * 2 + 1][hh * 64];
        _Float16* hout = h16 + (size_t)l2 * NN * HCH + (size_t)grow * HCH + hh * 64;
        float ds = 0.f, dd = 0.f;
#pragma unroll
        for (int i = 0; i < 8; ++i) {
            half8v v = *(half8v*)&eb[r][qq * 64 + i * 8];
            *(half8v*)(hout + i * 8) = v;
#pragma unroll
            for (int j = 0; j < 8; ++j) {
                float f = (float)v[j];
                ds = fmaf(f, avS[i * 8 + j], ds);
                dd = fmaf(f, avD[i * 8 + j], dd);
            }
        }
        a_s[(size_t)l2 * 2 * NN + 2 * grow + hh] = ds;
        a_d[(size_t)l2 * 2 * NN + 2 * grow + hh] = dd;
    }
}

// =================== K2: per-bucket LDS counting sort (grid (NB,2)) =========
__global__ __launch_bounds__(256) void sort_kernel(
    const int* __restrict__ gcursor, int* __restrict__ bstore,
    int* __restrict__ gstart, int* __restrict__ gend, int n)
{
    __shared__ int raw[CAP];
    __shared__ int sorted[CAP];
    __shared__ int curs[128];
    __shared__ int scanbuf[128];
    const int lay = blockIdx.y;
    const int* gcur = gcursor + lay * NB;
    int* bst = bstore + (size_t)lay * NB * CAP;
    int* gs = gstart + (size_t)lay * NN;
    int* ge = gend + (size_t)lay * NN;

    const int tid = threadIdx.x;
    const int b = blockIdx.x;
    const int node0 = b * NPB;
    const int nnode = min(NPB, n - node0);
    if (nnode <= 0) return;
    int cnt = gcur[b];
    cnt = cnt < 0 ? 0 : (cnt > CAP ? CAP : cnt);

    for (int i = tid; i < cnt; i += 256) raw[i] = bst[b * CAP + i];
    if (tid < 128) curs[tid] = 0;
    __syncthreads();
    for (int i = tid; i < cnt; i += 256) atomicAdd(&curs[raw[i] & 127], 1);
    __syncthreads();
    if (tid < 128) scanbuf[tid] = curs[tid];
    __syncthreads();
    for (int off = 1; off < 128; off <<= 1) {
        int v = 0;
        if (tid < 128) { v = scanbuf[tid]; if (tid >= off) v += scanbuf[tid - off]; }
        __syncthreads();
        if (tid < 128) scanbuf[tid] = v;
        __syncthreads();
    }
    if (tid < 128) {
        int ex = tid ? scanbuf[tid - 1] : 0;
        curs[tid] = ex;
        if (tid < nnode) {
            gs[node0 + tid] = b * CAP + ex;
            ge[node0 + tid] = b * CAP + scanbuf[tid];
        }
    }
    __syncthreads();
    for (int i = tid; i < cnt; i += 256) {
        int item = raw[i];
        int pos = atomicAdd(&curs[item & 127], 1);
        if (pos >= 0 && pos < CAP) sorted[pos] = item >> 7;
    }
    __syncthreads();
    for (int i = tid; i < cnt; i += 256) bst[b * CAP + i] = sorted[i];
}

// =================== K3: AGG, group-parallel nodes, layer-sequential ========
// grid (2*6250): blocks 0..6249 layer 0, 6250..12499 layer 1 -> gather
// working set halves (h16 layer = 25.6 MB) for better L2 hit rate.
__global__ __launch_bounds__(256) void agg_kernel(
    const _Float16* __restrict__ h16, const float2* __restrict__ a_s,
    const float2* __restrict__ a_d, const int* __restrict__ gstart,
    const int* __restrict__ gend, const int* __restrict__ bstore,
    const float* __restrict__ bias0, const float* __restrict__ bias1,
    _Float16* __restrict__ xc16, int n)
{
    __shared__ __align__(16) uint2 sh[4][64];   // [wave][group*16+slot]
    int bx = blockIdx.x;
    const int lay = bx >= AGG_X;
    bx -= lay ? AGG_X : 0;
    const _Float16* hL = h16 + (size_t)lay * NN * HCH;
    const float2* asL = a_s + (size_t)lay * NN;
    const float2* adL = a_d + (size_t)lay * NN;
    const int* gsL = gstart + (size_t)lay * NN;
    const int* geL = gend + (size_t)lay * NN;
    const int* ssort = bstore + (size_t)lay * NB * CAP;
    const float* bias = lay ? bias1 : bias0;

    const int wid = threadIdx.x >> 6, lane = threadIdx.x & 63;
    const int g = lane >> 4;          // group: which of the wave's 4 nodes
    const int i = lane & 15;          // lane-in-group: col group AND stage slot
    const int hh = i >> 3;            // head for these columns
    const u32 psel = hh ? 0x07060302u : 0x05040100u;
    const fp16x2 one2 = { (__fp16)1.f, (__fp16)1.f };

    const int node = bx * 16 + wid * 4 + g;
    const bool valid = node < n;
    const int nn = valid ? node : 0;

    float bv[8];
#pragma unroll
    for (int j = 0; j < 8; ++j) bv[j] = bias[i * 8 + j];

    int start = gsL[nn], end = geL[nn];
    start = start < 0 ? 0 : (start > NB * CAP ? NB * CAP : start);
    end = end < start ? start : (end > NB * CAP ? NB * CAP : end);
    const int cnt = end - start;
    const float2 ad = adL[nn];
    const float2 asn = asL[nn];

    float acc[8] = {0.f, 0.f, 0.f, 0.f, 0.f, 0.f, 0.f, 0.f};
    float den = 0.f;
    uint2* slots = &sh[wid][g * 16];

    for (int base = 0; base < cnt; base += 16) {
        const int idx = start + base + i;
        float p0 = 0.f, p1 = 0.f;
        int s = 0;
        if (idx < end) {
            s = ssort[idx];
            if ((unsigned)s >= (unsigned)n) s = 0;   // poison guard
            float2 a = asL[s];
            p0 = __expf(lrelu(a.x + ad.x));
            p1 = __expf(lrelu(a.y + ad.y));
        }
        H2U pk; pk.h = __builtin_amdgcn_cvt_pkrtz(p0, p1);
        slots[i] = make_uint2((u32)s, pk.u);
        __builtin_amdgcn_wave_barrier();
        const int c2 = min(16, cnt - base);
        for (int t = 0; t < c2; t += 2) {
            const uint4 rec = *(const uint4*)&slots[t];   // slots t, t+1
            H2U pph; pph.u = __builtin_amdgcn_perm(rec.w, rec.y, psel);
            const half8v hv0 = *(const half8v*)(hL + ((rec.x << 7) | (u32)(i << 3)));
            const half8v hv1 = *(const half8v*)(hL + ((rec.z << 7) | (u32)(i << 3)));
            const u32* ap = (const u32*)&hv0;
            const u32* bp = (const u32*)&hv1;
#pragma unroll
            for (int d2 = 0; d2 < 4; ++d2) {
                H2U pe, po;
                pe.u = __builtin_amdgcn_perm(bp[d2], ap[d2], 0x05040100u);
                po.u = __builtin_amdgcn_perm(bp[d2], ap[d2], 0x07060302u);
                acc[2 * d2]     = __builtin_amdgcn_fdot2(pe.h, pph.h, acc[2 * d2], false);
                acc[2 * d2 + 1] = __builtin_amdgcn_fdot2(po.h, pph.h, acc[2 * d2 + 1], false);
            }
            den = __builtin_amdgcn_fdot2(pph.h, one2, den, false);
        }
        __builtin_amdgcn_wave_barrier();
    }
    // self loop (parallel across groups; no reduce anywhere)
    {
        const float ps0 = __expf(lrelu(asn.x + ad.x));
        const float ps1 = __expf(lrelu(asn.y + ad.y));
        const half8v hv = *(const half8v*)(hL + (((u32)nn << 7) | (u32)(i << 3)));
        const float pl = hh ? ps1 : ps0;
#pragma unroll
        for (int j2 = 0; j2 < 8; ++j2)
            acc[j2] = fmaf(pl, (float)hv[j2], acc[j2]);
        den += pl;
    }
    if (valid) {
        const float inv = 1.f / den;
        half8v o;
#pragma unroll
        for (int j2 = 0; j2 < 8; ++j2)
            o[j2] = (_Float16)fmaxf(acc[j2] * inv + bv[j2], 0.f);
        *(half8v*)(xc16 + (size_t)node * 256 + lay * HCH + i * 8) = o;
    }
}

// =================== K4: FC via MFMA, K=256 concat ==========================
__global__ __launch_bounds__(256) void fc_mfma(const _Float16* __restrict__ xc16,
                                               const _Float16* __restrict__ fw2,
                                               const float* __restrict__ fcb,
                                               float* __restrict__ out, int n)
{
    __shared__ _Float16 axs[64][264];
    const int tid = threadIdx.x;
    const int lane = tid & 63, wave = tid >> 6;
    const int q = lane >> 4, r16 = lane & 15;
    const int row0 = blockIdx.x * 64;

    // stage A: 64 rows x 256 k (8 half8 loads/thread, coalesced)
#pragma unroll
    for (int i = 0; i < 8; ++i) {
        const int idx = i * 256 + tid;
        const int row = idx >> 5;
        const int kg = (idx & 31) * 8;
        half8v v = { 0, 0, 0, 0, 0, 0, 0, 0 };
        if (row0 + row < n)
            v = *(const half8v*)(xc16 + (size_t)(row0 + row) * 256 + kg);
        *(half8v*)&axs[row][kg] = v;
    }
    __syncthreads();

    float4v acc[4];
#pragma unroll
    for (int i = 0; i < 4; ++i) acc[i] = (float4v){0.f, 0.f, 0.f, 0.f};
#pragma unroll
    for (int s = 0; s < 8; ++s) {
        const half8v af = *(half8v*)&axs[wave * 16 + r16][s * 32 + q * 8];
#pragma unroll
        for (int nt = 0; nt < 4; ++nt) {
            const half8v bf =
                *(const half8v*)(fw2 + (size_t)(nt * 16 + r16) * 256 + s * 32 + q * 8);
            acc[nt] = __builtin_amdgcn_mfma_f32_16x16x32_f16(af, bf, acc[nt], 0, 0, 0);
        }
    }
#pragma unroll
    for (int nt = 0; nt < 4; ++nt) {
        const int col = nt * 16 + r16;
#pragma unroll
        for (int reg = 0; reg < 4; ++reg) {
            const int row = row0 + wave * 16 + q * 4 + reg;
            if (row < n)
                out[(size_t)row * OUT_DIM + col] = acc[nt][reg] + fcb[col];
        }
    }
}

// ---------------- launch ----------------
extern "C" void kernel_launch(void* const* d_in, const int* in_sizes, int n_in,
                              void* d_out, int out_size, void* d_ws, size_t ws_size,
                              hipStream_t stream)
{
    const float* x = (const float*)d_in[0];
    const int* ei[2] = { (const int*)d_in[1], (const int*)d_in[2] };
    const float* W[2] = { (const float*)d_in[3], (const float*)d_in[7] };
    const float* attS[2] = { (const float*)d_in[4], (const float*)d_in[8] };
    const float* attD[2] = { (const float*)d_in[5], (const float*)d_in[9] };
    const float* bias[2] = { (const float*)d_in[6], (const float*)d_in[10] };
    const float* fcW = (const float*)d_in[11];
    const float* fcb = (const float*)d_in[12];
    float* out = (float*)d_out;

    char* p = (char*)d_ws;
    size_t need = 0;
    auto carve = [&](size_t bytes) {
        char* r = p;
        size_t b = (bytes + 255) & ~(size_t)255;
        p += b;
        need += b;
        return r;
    };
    _Float16* h16 = (_Float16*)carve((size_t)2 * NN * HCH * 2);    // both layers
    _Float16* xc16 = (_Float16*)carve((size_t)NN * 256 * 2);       // concat rows
    _Float16* wt = (_Float16*)carve((size_t)2 * IN_DIM * HCH * 2);
    _Float16* fcw2 = (_Float16*)carve((size_t)256 * OUT_DIM * 2);
    float* a_s = (float*)carve((size_t)2 * NN * 8);                // [layer][node][head]
    float* a_d = (float*)carve((size_t)2 * NN * 8);
    int* gcursor = (int*)carve((size_t)2 * NB * 4);
    int* bstore = (int*)carve((size_t)2 * NB * CAP * 4);
    int* gstart = (int*)carve((size_t)2 * NN * 4);
    int* gend = (int*)carve((size_t)2 * NN * 4);
    if (need > ws_size) return;  // loud correctness failure instead of OOB crash

    // K0: weight convert + gcursor zero
    conv_kernel<<<CONV_BLOCKS + 1, 256, 0, stream>>>(W[0], W[1], fcW, wt, fcw2, gcursor);

    // K1: gemm || bucket (the two whales, complementary pipes)
    work_kernel<<<WORK_BLOCKS, 256, 0, stream>>>(
        x, wt, attS[0], attD[0], attS[1], attD[1],
        h16, a_s, a_d, ei[0], ei[1], gcursor, bstore, NN);

    // K2: sort (standalone, 17.4 KB LDS -> high occupancy)
    sort_kernel<<<dim3(NB, 2), 256, 0, stream>>>(gcursor, bstore, gstart, gend, NN);

    // K3: agg, layer-sequential for L2 locality
    agg_kernel<<<2 * AGG_X, 256, 0, stream>>>(
        h16, (const float2*)a_s, (const float2*)a_d,
        gstart, gend, bstore, bias[0], bias[1], xc16, NN);

    // K4: FC
    fc_mfma<<<GEMM_BLOCKS, 256, 0, stream>>>(xc16, fcw2, fcb, out, NN);
}

// Round 7
// 452.558 us; speedup vs baseline: 1.0577x; 1.0121x over previous
//
#include <hip/hip_runtime.h>
#include <hip/hip_fp16.h>
#include <math.h>

#define NN 100000
#define IN_DIM 256
#define HCH 128      // HEADS*HID
#define OUT_DIM 64
#define EE 1600000
#define NEG_SLOPE 0.2f

#define NB 1024      // dst buckets per layer
#define NPB 98       // nodes per bucket (1024*98 >= 100000)
#define CAP 2048     // bucket capacity (mean 1562, std ~40 -> 12 sigma margin)

#define GEMM_BLOCKS 1563     // (NN+63)/64
#define CONV_BLOCKS 320      // (2*256*128 + 256*64)/256
#define BUCKET_PER_LAYER 512 // 512 blocks x 3125 edges
#define BUCKET_BLOCKS (2 * BUCKET_PER_LAYER)
#define WORK_BLOCKS (GEMM_BLOCKS + BUCKET_BLOCKS)   // 2587
#define AGG_X ((NN + 15) / 16)                      // 6250

typedef _Float16 half8v __attribute__((ext_vector_type(8)));
typedef _Float16 half4v __attribute__((ext_vector_type(4)));
typedef __fp16 fp16x2 __attribute__((ext_vector_type(2)));   // clang builtin half2 type
typedef float float4v __attribute__((ext_vector_type(4)));
typedef unsigned int u32;

union H2U { u32 u; fp16x2 h; };

__device__ __forceinline__ float lrelu(float v) { return v > 0.f ? v : NEG_SLOPE * v; }

// =================== K0: convw + gcursor zero ===============================
__global__ __launch_bounds__(256) void conv_kernel(
    const float* __restrict__ W0, const float* __restrict__ W1,
    const float* __restrict__ fcW,
    _Float16* __restrict__ wt, _Float16* __restrict__ fcw2,
    int* __restrict__ gcursor)
{
    const int tid = threadIdx.x;
    if (blockIdx.x == CONV_BLOCKS) {
        for (int i = tid; i < 2 * NB; i += 256) gcursor[i] = 0;
        return;
    }
    int i = blockIdx.x * 256 + tid;
    if (i < 2 * IN_DIM * HCH) {
        int l = i >> 15, rem = i & 32767;
        int c = rem >> 8, k = rem & 255;
        const float* W = l ? W1 : W0;
        wt[i] = (_Float16)W[(size_t)k * HCH + c];
        return;
    }
    int j = i - 2 * IN_DIM * HCH;
    if (j < 256 * OUT_DIM) {
        int c = j >> 8, k = j & 255;   // fcw2[c*256 + k] = fcW[k][c]
        fcw2[j] = (_Float16)fcW[(size_t)k * OUT_DIM + c];
    }
}

// =================== K1: gemm (1563, BK=64)  ||  bucket (1024) ==============
// The two whales overlapped. gemm = proven R5 body (BK=64, 16 MFMA per
// barrier pair); launch_bounds(256,3) so acc[2][8] does NOT spill (R6 bug:
// (256,4) capped VGPR at 128 -> accumulator scratch spill, 145us).
// LDS 47.1 KB -> 3 blocks/CU.
__global__ __launch_bounds__(256, 3) void work_kernel(
    const float* __restrict__ x, const _Float16* __restrict__ wt,
    const float* __restrict__ attS0, const float* __restrict__ attD0,
    const float* __restrict__ attS1, const float* __restrict__ attD1,
    _Float16* __restrict__ h16, float* __restrict__ a_s, float* __restrict__ a_d,
    const int* __restrict__ ei0, const int* __restrict__ ei1,
    int* __restrict__ gcursor, int* __restrict__ bstore, int n)
{
    __shared__ __align__(16) _Float16 smem[64 * 72 + 256 * 72];  // 46.1 KB
    __shared__ float attv[4][128];
    const int tid = threadIdx.x;

    const long long TS = BUCKET_BLOCKS;                // 1024
    const long long TB = WORK_BLOCKS;                  // 2587
    const int k = blockIdx.x;
    const int slo = (int)(((long long)k * TS) / TB);
    const int shi = (int)(((long long)(k + 1) * TS) / TB);

    if (shi > slo) {
        // ---- bucket role ----
        int* hist = (int*)smem;
        int* base = hist + NB;
        const int bb = slo;                            // 0..1023
        const int lay = bb >> 9;
        const int idx = bb & 511;
        const int* src = lay ? ei1 : ei0;
        const int* dst = src + EE;
        int* gcur = gcursor + lay * NB;
        int* bst = bstore + (size_t)lay * NB * CAP;

        const int per = (EE + BUCKET_PER_LAYER - 1) / BUCKET_PER_LAYER;  // 3125
        const int e0 = idx * per;
        const int e1 = min(EE, e0 + per);
        for (int i = tid; i < NB; i += 256) hist[i] = 0;
        __syncthreads();
        for (int i = e0 + tid; i < e1; i += 256)
            atomicAdd(&hist[dst[i] / NPB], 1);
        __syncthreads();
        for (int b = tid; b < NB; b += 256) {
            int c = hist[b];
            base[b] = c ? atomicAdd(&gcur[b], c) : 0;
            hist[b] = 0;
        }
        __syncthreads();
        for (int i = e0 + tid; i < e1; i += 256) {
            int d = dst[i];
            int s = src[i];
            int b = d / NPB;
            int pos = base[b] + atomicAdd(&hist[b], 1);
            if (pos >= 0 && pos < CAP) bst[b * CAP + pos] = (s << 7) | (d - b * NPB);
        }
        return;
    }

    // ---- gemm role: fused dual-layer GEMM + attention-score epilogue ----
    _Float16 (*As)[72] = (_Float16(*)[72])smem;
    _Float16 (*Bs)[72] = (_Float16(*)[72])(smem + 64 * 72);
    const int gb = k - slo;                  // 0..1562
    const int lane = tid & 63, wave = tid >> 6;
    const int wm = wave & 1, wn = wave >> 1;
    const int q = lane >> 4, r16 = lane & 15;
    const int row0 = gb * 64;

    if (tid < 128) {
        attv[0][tid] = attS0[tid]; attv[1][tid] = attD0[tid];
        attv[2][tid] = attS1[tid]; attv[3][tid] = attD1[tid];
    }

    float4v acc[2][8];
#pragma unroll
    for (int i = 0; i < 2; ++i)
#pragma unroll
        for (int j = 0; j < 8; ++j) acc[i][j] = (float4v){0.f, 0.f, 0.f, 0.f};

    const int ar = tid >> 2, aq = tid & 3;   // A: row, k-quarter (16 floats)
    const bool rok = (row0 + ar) < n;
    for (int kt = 0; kt < IN_DIM; kt += 64) {
        const float* xp = x + (size_t)(row0 + ar) * IN_DIM + kt + aq * 16;
#pragma unroll
        for (int i = 0; i < 4; ++i) {
            float4 v = rok ? *(const float4*)(xp + i * 4) : make_float4(0.f, 0.f, 0.f, 0.f);
            half4v hv = { (_Float16)v.x, (_Float16)v.y, (_Float16)v.z, (_Float16)v.w };
            *(half4v*)&As[ar][aq * 16 + i * 4] = hv;
        }
        const _Float16* wp = wt + (size_t)tid * IN_DIM + kt;
#pragma unroll
        for (int i = 0; i < 8; ++i)
            *(half8v*)&Bs[tid][i * 8] = *(const half8v*)(wp + i * 8);
        __syncthreads();
#pragma unroll
        for (int s = 0; s < 2; ++s) {
            half8v af[2], bf[8];
#pragma unroll
            for (int t = 0; t < 2; ++t)
                af[t] = *(half8v*)&As[wm * 32 + t * 16 + r16][s * 32 + q * 8];
#pragma unroll
            for (int t = 0; t < 8; ++t)
                bf[t] = *(half8v*)&Bs[wn * 128 + t * 16 + r16][s * 32 + q * 8];
#pragma unroll
            for (int mt = 0; mt < 2; ++mt)
#pragma unroll
                for (int nt = 0; nt < 8; ++nt)
                    acc[mt][nt] = __builtin_amdgcn_mfma_f32_16x16x32_f16(
                        af[mt], bf[nt], acc[mt][nt], 0, 0, 0);
        }
        __syncthreads();
    }
    // epilogue: repack C to fp16 via LDS (C layout: row=q*4+reg, col=r16)
    _Float16 (*eb)[264] = (_Float16(*)[264])smem;
#pragma unroll
    for (int mt = 0; mt < 2; ++mt) {
        const int er = wm * 32 + mt * 16 + q * 4;
#pragma unroll
        for (int reg = 0; reg < 4; ++reg)
#pragma unroll
            for (int nt = 0; nt < 8; ++nt)
                eb[er + reg][wn * 128 + nt * 16 + r16] = (_Float16)acc[mt][nt][reg];
    }
    __syncthreads();
    const int r = tid >> 2, qq = tid & 3;    // qq: 64-col quarter -> (layer, head)
    const int grow = row0 + r;
    if (grow < n) {
        const int l2 = qq >> 1;
        const int hh = qq & 1;
        const float* avS = &attv[l2 * 2 + 0][hh * 64];
        const float* avD = &attv[l2 * 2 + 1][hh * 64];
        _Float16* hout = h16 + (size_t)l2 * NN * HCH + (size_t)grow * HCH + hh * 64;
        float ds = 0.f, dd = 0.f;
#pragma unroll
        for (int i = 0; i < 8; ++i) {
            half8v v = *(half8v*)&eb[r][qq * 64 + i * 8];
            *(half8v*)(hout + i * 8) = v;
#pragma unroll
            for (int j = 0; j < 8; ++j) {
                float f = (float)v[j];
                ds = fmaf(f, avS[i * 8 + j], ds);
                dd = fmaf(f, avD[i * 8 + j], dd);
            }
        }
        a_s[(size_t)l2 * 2 * NN + 2 * grow + hh] = ds;
        a_d[(size_t)l2 * 2 * NN + 2 * grow + hh] = dd;
    }
}

// =================== K2: per-bucket LDS counting sort (grid (NB,2)) =========
__global__ __launch_bounds__(256) void sort_kernel(
    const int* __restrict__ gcursor, int* __restrict__ bstore,
    int* __restrict__ gstart, int* __restrict__ gend, int n)
{
    __shared__ int raw[CAP];
    __shared__ int sorted[CAP];
    __shared__ int curs[128];
    __shared__ int scanbuf[128];
    const int lay = blockIdx.y;
    const int* gcur = gcursor + lay * NB;
    int* bst = bstore + (size_t)lay * NB * CAP;
    int* gs = gstart + (size_t)lay * NN;
    int* ge = gend + (size_t)lay * NN;

    const int tid = threadIdx.x;
    const int b = blockIdx.x;
    const int node0 = b * NPB;
    const int nnode = min(NPB, n - node0);
    if (nnode <= 0) return;
    int cnt = gcur[b];
    cnt = cnt < 0 ? 0 : (cnt > CAP ? CAP : cnt);

    for (int i = tid; i < cnt; i += 256) raw[i] = bst[b * CAP + i];
    if (tid < 128) curs[tid] = 0;
    __syncthreads();
    for (int i = tid; i < cnt; i += 256) atomicAdd(&curs[raw[i] & 127], 1);
    __syncthreads();
    if (tid < 128) scanbuf[tid] = curs[tid];
    __syncthreads();
    for (int off = 1; off < 128; off <<= 1) {
        int v = 0;
        if (tid < 128) { v = scanbuf[tid]; if (tid >= off) v += scanbuf[tid - off]; }
        __syncthreads();
        if (tid < 128) scanbuf[tid] = v;
        __syncthreads();
    }
    if (tid < 128) {
        int ex = tid ? scanbuf[tid - 1] : 0;
        curs[tid] = ex;
        if (tid < nnode) {
            gs[node0 + tid] = b * CAP + ex;
            ge[node0 + tid] = b * CAP + scanbuf[tid];
        }
    }
    __syncthreads();
    for (int i = tid; i < cnt; i += 256) {
        int item = raw[i];
        int pos = atomicAdd(&curs[item & 127], 1);
        if (pos >= 0 && pos < CAP) sorted[pos] = item >> 7;
    }
    __syncthreads();
    for (int i = tid; i < cnt; i += 256) bst[b * CAP + i] = sorted[i];
}

// =================== K3: AGG, group-parallel nodes, layer-sequential ========
__global__ __launch_bounds__(256) void agg_kernel(
    const _Float16* __restrict__ h16, const float2* __restrict__ a_s,
    const float2* __restrict__ a_d, const int* __restrict__ gstart,
    const int* __restrict__ gend, const int* __restrict__ bstore,
    const float* __restrict__ bias0, const float* __restrict__ bias1,
    _Float16* __restrict__ xc16, int n)
{
    __shared__ __align__(16) uint2 sh[4][64];   // [wave][group*16+slot]
    int bx = blockIdx.x;
    const int lay = bx >= AGG_X;
    bx -= lay ? AGG_X : 0;
    const _Float16* hL = h16 + (size_t)lay * NN * HCH;
    const float2* asL = a_s + (size_t)lay * NN;
    const float2* adL = a_d + (size_t)lay * NN;
    const int* gsL = gstart + (size_t)lay * NN;
    const int* geL = gend + (size_t)lay * NN;
    const int* ssort = bstore + (size_t)lay * NB * CAP;
    const float* bias = lay ? bias1 : bias0;

    const int wid = threadIdx.x >> 6, lane = threadIdx.x & 63;
    const int g = lane >> 4;          // group: which of the wave's 4 nodes
    const int i = lane & 15;          // lane-in-group: col group AND stage slot
    const int hh = i >> 3;            // head for these columns
    const u32 psel = hh ? 0x07060302u : 0x05040100u;
    const fp16x2 one2 = { (__fp16)1.f, (__fp16)1.f };

    const int node = bx * 16 + wid * 4 + g;
    const bool valid = node < n;
    const int nn = valid ? node : 0;

    float bv[8];
#pragma unroll
    for (int j = 0; j < 8; ++j) bv[j] = bias[i * 8 + j];

    int start = gsL[nn], end = geL[nn];
    start = start < 0 ? 0 : (start > NB * CAP ? NB * CAP : start);
    end = end < start ? start : (end > NB * CAP ? NB * CAP : end);
    const int cnt = end - start;
    const float2 ad = adL[nn];
    const float2 asn = asL[nn];

    float acc[8] = {0.f, 0.f, 0.f, 0.f, 0.f, 0.f, 0.f, 0.f};
    float den = 0.f;
    uint2* slots = &sh[wid][g * 16];

    for (int base = 0; base < cnt; base += 16) {
        const int idx = start + base + i;
        float p0 = 0.f, p1 = 0.f;
        int s = 0;
        if (idx < end) {
            s = ssort[idx];
            if ((unsigned)s >= (unsigned)n) s = 0;   // poison guard
            float2 a = asL[s];
            p0 = __expf(lrelu(a.x + ad.x));
            p1 = __expf(lrelu(a.y + ad.y));
        }
        H2U pk; pk.h = __builtin_amdgcn_cvt_pkrtz(p0, p1);
        slots[i] = make_uint2((u32)s, pk.u);
        __builtin_amdgcn_wave_barrier();
        const int c2 = min(16, cnt - base);
        for (int t = 0; t < c2; t += 2) {
            const uint4 rec = *(const uint4*)&slots[t];   // slots t, t+1
            H2U pph; pph.u = __builtin_amdgcn_perm(rec.w, rec.y, psel);
            const half8v hv0 = *(const half8v*)(hL + ((rec.x << 7) | (u32)(i << 3)));
            const half8v hv1 = *(const half8v*)(hL + ((rec.z << 7) | (u32)(i << 3)));
            const u32* ap = (const u32*)&hv0;
            const u32* bp = (const u32*)&hv1;
#pragma unroll
            for (int d2 = 0; d2 < 4; ++d2) {
                H2U pe, po;
                pe.u = __builtin_amdgcn_perm(bp[d2], ap[d2], 0x05040100u);
                po.u = __builtin_amdgcn_perm(bp[d2], ap[d2], 0x07060302u);
                acc[2 * d2]     = __builtin_amdgcn_fdot2(pe.h, pph.h, acc[2 * d2], false);
                acc[2 * d2 + 1] = __builtin_amdgcn_fdot2(po.h, pph.h, acc[2 * d2 + 1], false);
            }
            den = __builtin_amdgcn_fdot2(pph.h, one2, den, false);
        }
        __builtin_amdgcn_wave_barrier();
    }
    // self loop (parallel across groups; no reduce anywhere)
    {
        const float ps0 = __expf(lrelu(asn.x + ad.x));
        const float ps1 = __expf(lrelu(asn.y + ad.y));
        const half8v hv = *(const half8v*)(hL + (((u32)nn << 7) | (u32)(i << 3)));
        const float pl = hh ? ps1 : ps0;
#pragma unroll
        for (int j2 = 0; j2 < 8; ++j2)
            acc[j2] = fmaf(pl, (float)hv[j2], acc[j2]);
        den += pl;
    }
    if (valid) {
        const float inv = 1.f / den;
        half8v o;
#pragma unroll
        for (int j2 = 0; j2 < 8; ++j2)
            o[j2] = (_Float16)fmaxf(acc[j2] * inv + bv[j2], 0.f);
        *(half8v*)(xc16 + (size_t)node * 256 + lay * HCH + i * 8) = o;
    }
}

// =================== K4: FC via MFMA, K=256 concat ==========================
__global__ __launch_bounds__(256) void fc_mfma(const _Float16* __restrict__ xc16,
                                               const _Float16* __restrict__ fw2,
                                               const float* __restrict__ fcb,
                                               float* __restrict__ out, int n)
{
    __shared__ _Float16 axs[64][264];
    const int tid = threadIdx.x;
    const int lane = tid & 63, wave = tid >> 6;
    const int q = lane >> 4, r16 = lane & 15;
    const int row0 = blockIdx.x * 64;

    // stage A: 64 rows x 256 k (8 half8 loads/thread, coalesced)
#pragma unroll
    for (int i = 0; i < 8; ++i) {
        const int idx = i * 256 + tid;
        const int row = idx >> 5;
        const int kg = (idx & 31) * 8;
        half8v v = { 0, 0, 0, 0, 0, 0, 0, 0 };
        if (row0 + row < n)
            v = *(const half8v*)(xc16 + (size_t)(row0 + row) * 256 + kg);
        *(half8v*)&axs[row][kg] = v;
    }
    __syncthreads();

    float4v acc[4];
#pragma unroll
    for (int i = 0; i < 4; ++i) acc[i] = (float4v){0.f, 0.f, 0.f, 0.f};
#pragma unroll
    for (int s = 0; s < 8; ++s) {
        const half8v af = *(half8v*)&axs[wave * 16 + r16][s * 32 + q * 8];
#pragma unroll
        for (int nt = 0; nt < 4; ++nt) {
            const half8v bf =
                *(const half8v*)(fw2 + (size_t)(nt * 16 + r16) * 256 + s * 32 + q * 8);
            acc[nt] = __builtin_amdgcn_mfma_f32_16x16x32_f16(af, bf, acc[nt], 0, 0, 0);
        }
    }
#pragma unroll
    for (int nt = 0; nt < 4; ++nt) {
        const int col = nt * 16 + r16;
#pragma unroll
        for (int reg = 0; reg < 4; ++reg) {
            const int row = row0 + wave * 16 + q * 4 + reg;
            if (row < n)
                out[(size_t)row * OUT_DIM + col] = acc[nt][reg] + fcb[col];
        }
    }
}

// ---------------- launch ----------------
extern "C" void kernel_launch(void* const* d_in, const int* in_sizes, int n_in,
                              void* d_out, int out_size, void* d_ws, size_t ws_size,
                              hipStream_t stream)
{
    const float* x = (const float*)d_in[0];
    const int* ei[2] = { (const int*)d_in[1], (const int*)d_in[2] };
    const float* W[2] = { (const float*)d_in[3], (const float*)d_in[7] };
    const float* attS[2] = { (const float*)d_in[4], (const float*)d_in[8] };
    const float* attD[2] = { (const float*)d_in[5], (const float*)d_in[9] };
    const float* bias[2] = { (const float*)d_in[6], (const float*)d_in[10] };
    const float* fcW = (const float*)d_in[11];
    const float* fcb = (const float*)d_in[12];
    float* out = (float*)d_out;

    char* p = (char*)d_ws;
    size_t need = 0;
    auto carve = [&](size_t bytes) {
        char* r = p;
        size_t b = (bytes + 255) & ~(size_t)255;
        p += b;
        need += b;
        return r;
    };
    _Float16* h16 = (_Float16*)carve((size_t)2 * NN * HCH * 2);    // both layers
    _Float16* xc16 = (_Float16*)carve((size_t)NN * 256 * 2);       // concat rows
    _Float16* wt = (_Float16*)carve((size_t)2 * IN_DIM * HCH * 2);
    _Float16* fcw2 = (_Float16*)carve((size_t)256 * OUT_DIM * 2);
    float* a_s = (float*)carve((size_t)2 * NN * 8);                // [layer][node][head]
    float* a_d = (float*)carve((size_t)2 * NN * 8);
    int* gcursor = (int*)carve((size_t)2 * NB * 4);
    int* bstore = (int*)carve((size_t)2 * NB * CAP * 4);
    int* gstart = (int*)carve((size_t)2 * NN * 4);
    int* gend = (int*)carve((size_t)2 * NN * 4);
    if (need > ws_size) return;  // loud correctness failure instead of OOB crash

    // K0: weight convert + gcursor zero
    conv_kernel<<<CONV_BLOCKS + 1, 256, 0, stream>>>(W[0], W[1], fcW, wt, fcw2, gcursor);

    // K1: gemm (BK=64, no spill) || bucket
    work_kernel<<<WORK_BLOCKS, 256, 0, stream>>>(
        x, wt, attS[0], attD[0], attS[1], attD[1],
        h16, a_s, a_d, ei[0], ei[1], gcursor, bstore, NN);

    // K2: sort (standalone, high occupancy)
    sort_kernel<<<dim3(NB, 2), 256, 0, stream>>>(gcursor, bstore, gstart, gend, NN);

    // K3: agg, layer-sequential for L2 locality
    agg_kernel<<<2 * AGG_X, 256, 0, stream>>>(
        h16, (const float2*)a_s, (const float2*)a_d,
        gstart, gend, bstore, bias[0], bias[1], xc16, NN);

    // K4: FC
    fc_mfma<<<GEMM_BLOCKS, 256, 0, stream>>>(xc16, fcw2, fcb, out, NN);
}